// Round 1
// baseline (735.369 us; speedup 1.0000x reference)
//
#include <hip/hip_runtime.h>

// ResnetHyper: pref/chunk MLP (fp32) + huge einsum out[c,k,w] = rep[c,:] . ws[k,w,:]
// MLP exact in fp32 (tiny). Big GEMM (M=105,K=512,N=220000) via bf16 MFMA,
// memory-bound on streaming ws (460.8 MB fp32). rep emitted in MFMA A-fragment
// order so the GEMM kernel needs no LDS and no __syncthreads.
//
// R1 change: explicit 2-stage ws software pipeline with issue order
//   cvt(s) -> mfma(s) -> A-prefetch(s+1) -> ws-prefetch(s+2)
// so the compiler's vmcnt waits never drain in-flight HBM prefetches, plus
// __launch_bounds__(64) to lift the default 1024-thread 128-VGPR budget
// (prevents scratch spills / forced de-pipelining). Memset folded into MLP.

typedef __bf16 bf16x8 __attribute__((ext_vector_type(8)));
typedef float f32x4 __attribute__((ext_vector_type(4)));

#define NUM_CHUNKS 105
#define HIDDEN 512
#define N_COLS 220000   // 11 * 20000
#define PAD_CHUNKS 112  // 7 M-tiles * 16

// ---------------- Kernel 1: MLP -> rep bf16 in MFMA A-fragment layout --------
// grid: 112 blocks x 256 threads; blocks 105..111 zero the padded fragment slots
__global__ void mlp_kernel(const float* __restrict__ pref,       // [2]
                           const float* __restrict__ pref_emb,   // [2][64]
                           const float* __restrict__ chunk_emb,  // [105][64]
                           const float* __restrict__ W1, const float* __restrict__ b1,
                           const float* __restrict__ W2, const float* __restrict__ b2,
                           const float* __restrict__ W3, const float* __restrict__ b3,
                           __bf16* __restrict__ repf) {
  __shared__ float x[128];
  __shared__ float h1[512];
  __shared__ float h2[512];
  const int tid = threadIdx.x;
  const int c = blockIdx.x;
  const int t = c >> 4, mmc = c & 15;

  if (c >= NUM_CHUNKS) {
    // padded chunks m=105..111: fragment slots must be zero
    for (int jj = tid; jj < 512; jj += 256) {
      const int ss = jj >> 5, qq = (jj >> 3) & 3, j = jj & 7;
      const long idx = (((long)(ss * 7 + t) * 4 + qq) * 16 + mmc) * 8 + j;
      repf[idx] = (__bf16)0.f;
    }
    return;
  }

  if (tid < 64) {
    x[tid] = pref[0] * pref_emb[tid] + pref[1] * pref_emb[64 + tid];
  } else if (tid < 128) {
    x[tid] = chunk_emb[c * 64 + (tid - 64)];
  }
  __syncthreads();

  // layer 1: h1 = relu(x @ W1.T + b1), W1[j] is 128 contiguous floats
  for (int jj = tid; jj < 512; jj += 256) {
    float s = b1[jj];
    const f32x4* wr = (const f32x4*)(W1 + jj * 128);
#pragma unroll
    for (int i = 0; i < 32; ++i) {
      f32x4 w = wr[i];
      s += w[0] * x[i * 4 + 0] + w[1] * x[i * 4 + 1] +
           w[2] * x[i * 4 + 2] + w[3] * x[i * 4 + 3];
    }
    h1[jj] = fmaxf(s, 0.f);
  }
  __syncthreads();

  // layer 2
  for (int jj = tid; jj < 512; jj += 256) {
    float s = b2[jj];
    const f32x4* wr = (const f32x4*)(W2 + jj * 512);
#pragma unroll 8
    for (int i = 0; i < 128; ++i) {
      f32x4 w = wr[i];
      s += w[0] * h1[i * 4 + 0] + w[1] * h1[i * 4 + 1] +
           w[2] * h1[i * 4 + 2] + w[3] * h1[i * 4 + 3];
    }
    h2[jj] = fmaxf(s, 0.f);
  }
  __syncthreads();

  // layer 3 (no relu) + scatter into A-fragment layout:
  // for chunk m=c, k=jj:  s=k>>5, q=(k>>3)&3, j=k&7, t=m>>4, mm=m&15
  for (int jj = tid; jj < 512; jj += 256) {
    float s = b3[jj];
    const f32x4* wr = (const f32x4*)(W3 + jj * 512);
#pragma unroll 8
    for (int i = 0; i < 128; ++i) {
      f32x4 w = wr[i];
      s += w[0] * h2[i * 4 + 0] + w[1] * h2[i * 4 + 1] +
           w[2] * h2[i * 4 + 2] + w[3] * h2[i * 4 + 3];
    }
    const int ss = jj >> 5, qq = (jj >> 3) & 3, j = jj & 7;
    const long idx = (((long)(ss * 7 + t) * 4 + qq) * 16 + mmc) * 8 + j;
    repf[idx] = (__bf16)s;
  }
}

// ---------------- Kernel 2: C[105 x 220000] = rep @ ws^T via bf16 MFMA -------
// grid: 6875 blocks x 64 threads (1 wave/block, 32 N-cols per wave)
// Explicit pipeline: ws stages 2 deep (HBM), A-fragments 1 deep (L2).
__global__ __launch_bounds__(64) void gemm_ws(
    const float* __restrict__ ws,    // [220000][512]
    const bf16x8* __restrict__ repf, // fragment chunks
    float* __restrict__ out) {       // [105][220000]
  const int lane = threadIdx.x;   // 0..63
  const int q = lane >> 4;
  const int mm = lane & 15;
  const long cb = (long)blockIdx.x * 32;
  const long col0 = cb + mm;
  const long col1 = col0 + 16;

  // per K-step s (32 elems): lane loads ws[col][s*32 + q*8 .. +8)
  const f32x4* w0 = (const f32x4*)(ws + col0 * 512) + q * 2;
  const f32x4* w1 = (const f32x4*)(ws + col1 * 512) + q * 2;

  f32x4 acc0[7], acc1[7];
#pragma unroll
  for (int t = 0; t < 7; ++t) {
    acc0[t] = (f32x4){0.f, 0.f, 0.f, 0.f};
    acc1[t] = (f32x4){0.f, 0.f, 0.f, 0.f};
  }

  // pipeline registers
  f32x4 X0[2], X1[2], Y0[2], Y1[2];
  bf16x8 A[7];

  // Prologue issue order: ws(0), A(0), ws(1)  -- A(0) issued before ws(1) so
  // the mfma(0) wait does not force ws(1) completion.
  X0[0] = __builtin_nontemporal_load(w0 + 0);
  X1[0] = __builtin_nontemporal_load(w0 + 1);
  Y0[0] = __builtin_nontemporal_load(w1 + 0);
  Y1[0] = __builtin_nontemporal_load(w1 + 1);
  {
    const bf16x8* ap = repf + lane;
#pragma unroll
    for (int t = 0; t < 7; ++t) A[t] = ap[t * 64];
  }
  X0[1] = __builtin_nontemporal_load(w0 + 8);
  X1[1] = __builtin_nontemporal_load(w0 + 9);
  Y0[1] = __builtin_nontemporal_load(w1 + 8);
  Y1[1] = __builtin_nontemporal_load(w1 + 9);

#pragma unroll
  for (int s = 0; s < 16; ++s) {
    const int slot = s & 1;
    // (1) convert current ws stage to bf16 — waits only on ws(s)
    f32x4 x0 = X0[slot], x1 = X1[slot], y0 = Y0[slot], y1 = Y1[slot];
    bf16x8 b0, b1;
#pragma unroll
    for (int j = 0; j < 4; ++j) {
      b0[j] = (__bf16)x0[j];
      b0[4 + j] = (__bf16)x1[j];
      b1[j] = (__bf16)y0[j];
      b1[4 + j] = (__bf16)y1[j];
    }
    // (2) MFMA with resident A(s) — newest outstanding loads are only ws(s+1),
    //     so the implied vmcnt never drains the deep prefetch
#pragma unroll
    for (int t = 0; t < 7; ++t) {
      acc0[t] = __builtin_amdgcn_mfma_f32_16x16x32_bf16(A[t], b0, acc0[t], 0, 0, 0);
      acc1[t] = __builtin_amdgcn_mfma_f32_16x16x32_bf16(A[t], b1, acc1[t], 0, 0, 0);
    }
    // (3) prefetch A(s+1) from L2-resident repf
    if (s < 15) {
      const bf16x8* ap = repf + (s + 1) * 448 + lane;
#pragma unroll
      for (int t = 0; t < 7; ++t) A[t] = ap[t * 64];
    }
    // (4) prefetch ws(s+2) into the stage we just consumed
    if (s < 14) {
      X0[slot] = __builtin_nontemporal_load(w0 + (s + 2) * 8);
      X1[slot] = __builtin_nontemporal_load(w0 + (s + 2) * 8 + 1);
      Y0[slot] = __builtin_nontemporal_load(w1 + (s + 2) * 8);
      Y1[slot] = __builtin_nontemporal_load(w1 + (s + 2) * 8 + 1);
    }
  }

  // C/D layout: col = lane&15, row = (lane>>4)*4 + reg  (per M-tile t: +t*16)
#pragma unroll
  for (int t = 0; t < 7; ++t) {
    const int mbase = t * 16 + q * 4;
#pragma unroll
    for (int r = 0; r < 4; ++r) {
      const int m = mbase + r;
      if (m < NUM_CHUNKS) {
        __builtin_nontemporal_store(acc0[t][r], out + (long)m * N_COLS + col0);
        __builtin_nontemporal_store(acc1[t][r], out + (long)m * N_COLS + col1);
      }
    }
  }
}

extern "C" void kernel_launch(void* const* d_in, const int* in_sizes, int n_in,
                              void* d_out, int out_size, void* d_ws, size_t ws_size,
                              hipStream_t stream) {
  const float* pref      = (const float*)d_in[0];
  const float* pref_emb  = (const float*)d_in[1];
  const float* chunk_emb = (const float*)d_in[2];
  const float* W1 = (const float*)d_in[3];
  const float* b1 = (const float*)d_in[4];
  const float* W2 = (const float*)d_in[5];
  const float* b2 = (const float*)d_in[6];
  const float* W3 = (const float*)d_in[7];
  const float* b3 = (const float*)d_in[8];
  const float* ws = (const float*)d_in[9];
  float* out = (float*)d_out;
  __bf16* repf = (__bf16*)d_ws;

  // pad blocks (c=105..111) zero their fragment slots; no memset needed
  mlp_kernel<<<PAD_CHUNKS, 256, 0, stream>>>(pref, pref_emb, chunk_emb,
                                             W1, b1, W2, b2, W3, b3, repf);
  gemm_ws<<<N_COLS / 32, 64, 0, stream>>>(ws, (const bf16x8*)d_ws, out);
}

// Round 2
// 719.646 us; speedup vs baseline: 1.0218x; 1.0218x over previous
//
#include <hip/hip_runtime.h>

// ResnetHyper: pref/chunk MLP (fp32) + huge einsum out[c,k,w] = rep[c,:] . ws[k,w,:]
// MLP exact in fp32 (tiny). Big GEMM (M=105,K=512,N=220000) via bf16 MFMA,
// memory-bound on streaming ws (450.6 MB fp32).
//
// R2 change: 4-wave blocks stage the full 114 KB rep fragment buffer into LDS
// once per block (global_load_lds, linear). A-fragments now come from LDS
// (ds_read_b128, conflict-free), so (a) repf no longer depends on L2 surviving
// the 450 MB ws stream (suspected HBM fallback = 784 MB extra traffic), and
// (b) the VMEM FIFO is a pure ws stream with clean depth-3 prefetch (no
// vmcnt coupling between L2 A-loads and HBM ws-loads).

typedef __bf16 bf16x8 __attribute__((ext_vector_type(8)));
typedef float f32x4 __attribute__((ext_vector_type(4)));

#define NUM_CHUNKS 105
#define HIDDEN 512
#define N_COLS 220000   // 11 * 20000
#define PAD_CHUNKS 112  // 7 M-tiles * 16
#define REP_CHUNKS 7168 // bf16x8 chunks = 114688 B

// ---------------- Kernel 1: MLP -> rep bf16 in MFMA A-fragment layout --------
// grid: 112 blocks x 256 threads; blocks 105..111 zero the padded fragment slots
__global__ void mlp_kernel(const float* __restrict__ pref,       // [2]
                           const float* __restrict__ pref_emb,   // [2][64]
                           const float* __restrict__ chunk_emb,  // [105][64]
                           const float* __restrict__ W1, const float* __restrict__ b1,
                           const float* __restrict__ W2, const float* __restrict__ b2,
                           const float* __restrict__ W3, const float* __restrict__ b3,
                           __bf16* __restrict__ repf) {
  __shared__ float x[128];
  __shared__ float h1[512];
  __shared__ float h2[512];
  const int tid = threadIdx.x;
  const int c = blockIdx.x;
  const int t = c >> 4, mmc = c & 15;

  if (c >= NUM_CHUNKS) {
    for (int jj = tid; jj < 512; jj += 256) {
      const int ss = jj >> 5, qq = (jj >> 3) & 3, j = jj & 7;
      const long idx = (((long)(ss * 7 + t) * 4 + qq) * 16 + mmc) * 8 + j;
      repf[idx] = (__bf16)0.f;
    }
    return;
  }

  if (tid < 64) {
    x[tid] = pref[0] * pref_emb[tid] + pref[1] * pref_emb[64 + tid];
  } else if (tid < 128) {
    x[tid] = chunk_emb[c * 64 + (tid - 64)];
  }
  __syncthreads();

  // layer 1: h1 = relu(x @ W1.T + b1), W1[j] is 128 contiguous floats
  for (int jj = tid; jj < 512; jj += 256) {
    float s = b1[jj];
    const f32x4* wr = (const f32x4*)(W1 + jj * 128);
#pragma unroll
    for (int i = 0; i < 32; ++i) {
      f32x4 w = wr[i];
      s += w[0] * x[i * 4 + 0] + w[1] * x[i * 4 + 1] +
           w[2] * x[i * 4 + 2] + w[3] * x[i * 4 + 3];
    }
    h1[jj] = fmaxf(s, 0.f);
  }
  __syncthreads();

  // layer 2
  for (int jj = tid; jj < 512; jj += 256) {
    float s = b2[jj];
    const f32x4* wr = (const f32x4*)(W2 + jj * 512);
#pragma unroll 8
    for (int i = 0; i < 128; ++i) {
      f32x4 w = wr[i];
      s += w[0] * h1[i * 4 + 0] + w[1] * h1[i * 4 + 1] +
           w[2] * h1[i * 4 + 2] + w[3] * h1[i * 4 + 3];
    }
    h2[jj] = fmaxf(s, 0.f);
  }
  __syncthreads();

  // layer 3 (no relu) + scatter into A-fragment layout:
  // for chunk m=c, k=jj:  s=k>>5, q=(k>>3)&3, j=k&7, t=m>>4, mm=m&15
  for (int jj = tid; jj < 512; jj += 256) {
    float s = b3[jj];
    const f32x4* wr = (const f32x4*)(W3 + jj * 512);
#pragma unroll 8
    for (int i = 0; i < 128; ++i) {
      f32x4 w = wr[i];
      s += w[0] * h2[i * 4 + 0] + w[1] * h2[i * 4 + 1] +
           w[2] * h2[i * 4 + 2] + w[3] * h2[i * 4 + 3];
    }
    const int ss = jj >> 5, qq = (jj >> 3) & 3, j = jj & 7;
    const long idx = (((long)(ss * 7 + t) * 4 + qq) * 16 + mmc) * 8 + j;
    repf[idx] = (__bf16)s;
  }
}

// ---------------- Kernel 2: C[105 x 220000] = rep @ ws^T via bf16 MFMA -------
// grid: ceil(220000/128) = 1719 blocks x 256 threads (4 waves, 32 cols/wave).
// repf staged in LDS once per block; ws depth-3 register pipeline.
__global__ __launch_bounds__(256, 1) void gemm_ws(
    const float* __restrict__ ws,    // [220000][512]
    const bf16x8* __restrict__ repf, // fragment chunks (linear)
    float* __restrict__ out) {       // [105][220000]
  __shared__ bf16x8 Alds[REP_CHUNKS];  // 114688 B

  const int tid = threadIdx.x;
  const int lane = tid & 63;
  const int wv = tid >> 6;        // wave 0..3
  const int q = lane >> 4;
  const int mm = lane & 15;

  // ---- stage repf -> LDS, linear (dest order == source order) ----
  // each wave: 28 x 1KB chunks; lds dest is wave-uniform base + lane*16
#pragma unroll
  for (int i = 0; i < 28; ++i) {
    const bf16x8* g = repf + wv * 1792 + i * 64 + lane;
    __builtin_amdgcn_global_load_lds(
        (const __attribute__((address_space(1))) unsigned int*)g,
        (__attribute__((address_space(3))) unsigned int*)&Alds[wv * 1792 + i * 64],
        16, 0, 0);
  }

  // ---- output columns for this wave ----
  const long cb = (long)blockIdx.x * 128 + wv * 32;
  const long col0 = cb + mm;
  const long col1 = col0 + 16;
  const bool v0 = col0 < N_COLS;
  const bool v1 = col1 < N_COLS;
  const long cl0 = v0 ? col0 : 0;   // clamp OOB loads to row 0 (discarded)
  const long cl1 = v1 ? col1 : 0;
  const f32x4* w0 = (const f32x4*)(ws + cl0 * 512) + q * 2;
  const f32x4* w1 = (const f32x4*)(ws + cl1 * 512) + q * 2;

  // ---- ws prologue s=0..2 issued BEFORE the barrier: its HBM latency hides
  //      under the barrier's staging drain ----
  f32x4 X0[3], X1[3], Y0[3], Y1[3];
#pragma unroll
  for (int p = 0; p < 3; ++p) {
    X0[p] = __builtin_nontemporal_load(w0 + p * 8);
    X1[p] = __builtin_nontemporal_load(w0 + p * 8 + 1);
    Y0[p] = __builtin_nontemporal_load(w1 + p * 8);
    Y1[p] = __builtin_nontemporal_load(w1 + p * 8 + 1);
  }

  __syncthreads();  // staging + prologue complete

  f32x4 acc0[7], acc1[7];
#pragma unroll
  for (int t = 0; t < 7; ++t) {
    acc0[t] = (f32x4){0.f, 0.f, 0.f, 0.f};
    acc1[t] = (f32x4){0.f, 0.f, 0.f, 0.f};
  }

  // A double-buffer from LDS (static parity indexing after full unroll)
  bf16x8 Aa[7], Ab[7];
#pragma unroll
  for (int t = 0; t < 7; ++t) Aa[t] = Alds[t * 64 + lane];  // A(0)

#pragma unroll
  for (int s = 0; s < 16; ++s) {
    // prefetch A(s+1) from LDS into the other buffer
    if (s < 15) {
#pragma unroll
      for (int t = 0; t < 7; ++t) {
        if (s & 1) Aa[t] = Alds[(s + 1) * 448 + t * 64 + lane];
        else       Ab[t] = Alds[(s + 1) * 448 + t * 64 + lane];
      }
    }
    // convert ws stage s (waits only on its own loads; VMEM FIFO is pure ws)
    const int slot = s % 3;
    f32x4 x0 = X0[slot], x1 = X1[slot], y0 = Y0[slot], y1 = Y1[slot];
    bf16x8 b0, b1;
#pragma unroll
    for (int j = 0; j < 4; ++j) {
      b0[j] = (__bf16)x0[j];
      b0[4 + j] = (__bf16)x1[j];
      b1[j] = (__bf16)y0[j];
      b1[4 + j] = (__bf16)y1[j];
    }
    // MFMA with current A buffer
#pragma unroll
    for (int t = 0; t < 7; ++t) {
      bf16x8 a = (s & 1) ? Ab[t] : Aa[t];
      acc0[t] = __builtin_amdgcn_mfma_f32_16x16x32_bf16(a, b0, acc0[t], 0, 0, 0);
      acc1[t] = __builtin_amdgcn_mfma_f32_16x16x32_bf16(a, b1, acc1[t], 0, 0, 0);
    }
    // refill consumed slot with ws(s+3)
    if (s < 13) {
      X0[slot] = __builtin_nontemporal_load(w0 + (s + 3) * 8);
      X1[slot] = __builtin_nontemporal_load(w0 + (s + 3) * 8 + 1);
      Y0[slot] = __builtin_nontemporal_load(w1 + (s + 3) * 8);
      Y1[slot] = __builtin_nontemporal_load(w1 + (s + 3) * 8 + 1);
    }
  }

  // C/D layout: col = lane&15, row = (lane>>4)*4 + reg  (per M-tile t: +t*16)
#pragma unroll
  for (int t = 0; t < 7; ++t) {
    const int mbase = t * 16 + q * 4;
#pragma unroll
    for (int r = 0; r < 4; ++r) {
      const int m = mbase + r;
      if (m < NUM_CHUNKS) {
        if (v0) __builtin_nontemporal_store(acc0[t][r], out + (long)m * N_COLS + col0);
        if (v1) __builtin_nontemporal_store(acc1[t][r], out + (long)m * N_COLS + col1);
      }
    }
  }
}

extern "C" void kernel_launch(void* const* d_in, const int* in_sizes, int n_in,
                              void* d_out, int out_size, void* d_ws, size_t ws_size,
                              hipStream_t stream) {
  const float* pref      = (const float*)d_in[0];
  const float* pref_emb  = (const float*)d_in[1];
  const float* chunk_emb = (const float*)d_in[2];
  const float* W1 = (const float*)d_in[3];
  const float* b1 = (const float*)d_in[4];
  const float* W2 = (const float*)d_in[5];
  const float* b2 = (const float*)d_in[6];
  const float* W3 = (const float*)d_in[7];
  const float* b3 = (const float*)d_in[8];
  const float* ws = (const float*)d_in[9];
  float* out = (float*)d_out;
  __bf16* repf = (__bf16*)d_ws;

  // pad blocks (c=105..111) zero their fragment slots; no memset needed
  mlp_kernel<<<PAD_CHUNKS, 256, 0, stream>>>(pref, pref_emb, chunk_emb,
                                             W1, b1, W2, b2, W3, b3, repf);
  const int nblk = (N_COLS + 127) / 128;  // 1719
  gemm_ws<<<nblk, 256, 0, stream>>>(ws, (const bf16x8*)d_ws, out);
}